// Round 1
// baseline (18965.353 us; speedup 1.0000x reference)
//
#include <hip/hip_runtime.h>
#include <math.h>

#define NB 64
#define ND 2048
#define NE 512
#define NM 25
#define NOUT 4096
#define NHEADS 8
#define NDH 64
#define NS 64
#define NITER 50
#define NKSYN 2560
#define NSPLIT 16
#define PRED_TOTAL (NB * NOUT * NITER)   /* 13107200 */

__device__ __forceinline__ float sigm(float x) { return 1.f / (1.f + expf(-x)); }

__device__ __forceinline__ float wredsum(float v) {
#pragma unroll
    for (int o = 32; o; o >>= 1) v += __shfl_xor(v, o);
    return v;
}
__device__ __forceinline__ float wredmax(float v) {
#pragma unroll
    for (int o = 32; o; o >>= 1) v = fmaxf(v, __shfl_xor(v, o));
    return v;
}

// OP: 0 = sum, 1 = max. red must hold >= blockDim.x/64 floats.
template <int OP>
__device__ __forceinline__ float blockReduce(float v, float* red) {
    const int tid = threadIdx.x, lane = tid & 63, wid = tid >> 6;
    v = (OP == 0) ? wredsum(v) : wredmax(v);
    __syncthreads();                 // protect red from previous use
    if (lane == 0) red[wid] = v;
    __syncthreads();
    if (tid == 0) {
        const int nw = blockDim.x >> 6;
        float r = red[0];
        for (int w = 1; w < nw; ++w) r = (OP == 0) ? r + red[w] : fmaxf(r, red[w]);
        red[0] = r;
    }
    __syncthreads();
    return red[0];
}

// ---------------- one-time precompute ----------------

// r_a, r_o, b_qq = q_b @ wq + bq. single block, 512 threads.
__global__ __launch_bounds__(512) void k_p0(const float* __restrict__ dec_a,
                                            const float* __restrict__ dec_o,
                                            const float* __restrict__ q_b,
                                            const float* __restrict__ wq,
                                            const float* __restrict__ bq,
                                            float* __restrict__ r_a, float* __restrict__ r_o,
                                            float* __restrict__ b_qq) {
    const int t = threadIdx.x;
    float da = fminf(fmaxf(dec_a[t], 0.f), 15.f);
    r_a[t] = expf(-da);
    float dn = fminf(fmaxf(dec_o[t], 0.f), 15.f);
    r_o[t] = expf(-dn);
    float acc = bq[t];
    for (int k = 0; k < NE; ++k) acc += q_b[k] * wq[k * NE + t];
    b_qq[t] = acc;
}

// W_qq[r][c] = sum_k q_w[r][k] * wq[k][c].  grid 1024 x 256
__global__ __launch_bounds__(256) void k_wqq(const float* __restrict__ q_w,
                                             const float* __restrict__ wq,
                                             float* __restrict__ W_qq) {
    const int idx = blockIdx.x * 256 + threadIdx.x;
    const int r = idx >> 9, c = idx & 511;
    float acc = 0.f;
    for (int k = 0; k < NE; ++k) acc += q_w[r * NE + k] * wq[k * NE + c];
    W_qq[idx] = acc;
}

// traceBuf[b][m][n] = start_trace[n][m].  grid 12800 x 256
__global__ __launch_bounds__(256) void k_init_trace(const float* __restrict__ st,
                                                    float* __restrict__ traceBuf) {
    const int idx = blockIdx.x * 256 + threadIdx.x;
    const int n = idx & (ND - 1);
    const int m = (idx / ND) % NM;
    traceBuf[idx] = st[n * NM + m];
}

// act init into preT + zero aA,bA,aO,bO (contiguous span).  grid 1024 x 256
__global__ __launch_bounds__(256) void k_init_state(const float* __restrict__ sa,
                                                    float* __restrict__ preT,
                                                    float* __restrict__ zeroBase) {
    const int idx = blockIdx.x * 256 + threadIdx.x;
    if (idx < NB * ND) {
        const int b = idx & 63, n = idx >> 6;
        preT[(NE + n) * NB + b] = sa[n];
    } else {
        zeroBase[idx - NB * ND] = 0.f;
    }
}

// kv = LN(feats @ kv_w + kv_b); kp_t/vp_t precompute. grid 4096 (b*64+s) x 512
__global__ __launch_bounds__(512) void k_p1(const float* __restrict__ x,
                                            const float* __restrict__ kv_w,
                                            const float* __restrict__ kv_b,
                                            const float* __restrict__ ln_g,
                                            const float* __restrict__ ln_b,
                                            const float* __restrict__ wk,
                                            const float* __restrict__ bk,
                                            const float* __restrict__ wv,
                                            const float* __restrict__ bv,
                                            float* __restrict__ kp_t,
                                            float* __restrict__ vp_t) {
    __shared__ float kvS[NE];
    __shared__ float red[16];
    const int b = blockIdx.x >> 6, s = blockIdx.x & 63;
    const int e = threadIdx.x;
    float acc = kv_b[e];
#pragma unroll
    for (int c = 0; c < 12; ++c) acc += x[b * 768 + c * 64 + s] * kv_w[c * NE + e];
    const float m = blockReduce<0>(acc, red) * (1.f / NE);
    const float d = acc - m;
    const float v = blockReduce<0>(d * d, red) * (1.f / NE);
    const float kvn = d * rsqrtf(v + 1e-5f) * ln_g[e] + ln_b[e];
    kvS[e] = kvn;
    __syncthreads();
    const int j = e;
    float kpv = bk[j], vpv = bv[j];
    for (int k = 0; k < NE; ++k) {
        const float kve = kvS[k];
        kpv += kve * wk[k * NE + j];
        vpv += kve * wv[k * NE + j];
    }
    const int h = j >> 6, dd = j & 63;
    kp_t[((b * NHEADS + h) * NDH + dd) * NS + s] = kpv;   // [b][h][d][s]
    vp_t[((b * NHEADS + h) * NS + s) * NDH + dd] = vpv;   // [b][h][s][d]
}

// ---------------- per-step kernels ----------------

// KA: sync_a, qh = sync_a @ W_qq + b_qq, attention, attn_out -> preT rows [0,512)
// grid 64 (b) x 512
__global__ __launch_bounds__(512) void k_front(float* __restrict__ preT,
                                               float* __restrict__ aA, float* __restrict__ bA,
                                               const float* __restrict__ r_a,
                                               const int* __restrict__ ial,
                                               const int* __restrict__ iar,
                                               const float* __restrict__ W_qq,
                                               const float* __restrict__ b_qq,
                                               const float* __restrict__ kp_t,
                                               const float* __restrict__ vp_t,
                                               const float* __restrict__ wo,
                                               const float* __restrict__ bo) {
    __shared__ float syncS[NE];
    __shared__ float qhS[NE];
    __shared__ float attnS[NE];
    __shared__ float oS[NE];
    const int b = blockIdx.x;
    const int tid = threadIdx.x;

    // phase 1: action sync
    {
        const int i = tid;
        const float av = preT[(NE + ial[i]) * NB + b] * preT[(NE + iar[i]) * NB + b];
        const float r = r_a[i];
        const float aN = r * aA[b * NE + i] + av;
        const float bN = r * bA[b * NE + i] + 1.f;
        aA[b * NE + i] = aN;
        bA[b * NE + i] = bN;
        syncS[i] = aN * rsqrtf(bN);
    }
    __syncthreads();
    // phase 2: qh
    {
        const int j = tid;
        float acc = b_qq[j];
        for (int k = 0; k < NE; ++k) acc += syncS[k] * W_qq[k * NE + j];
        qhS[j] = acc;
    }
    __syncthreads();
    // phase 3: scores + softmax (one wave per head)
    {
        const int h = tid >> 6, s = tid & 63;
        float sc = 0.f;
        const float* kpp = kp_t + ((b * NHEADS + h) * NDH) * NS + s;
        for (int d = 0; d < NDH; ++d) sc += qhS[h * NDH + d] * kpp[d * NS];
        sc *= 0.125f;
        const float mx = wredmax(sc);
        const float ev = expf(sc - mx);
        const float sm = wredsum(ev);
        attnS[h * NS + s] = ev / sm;
    }
    __syncthreads();
    // phase 4: o = attn @ V
    {
        const int h = tid >> 6, d = tid & 63;
        float o = 0.f;
        const float* vpp = vp_t + ((b * NHEADS + h) * NS) * NDH + d;
        for (int s2 = 0; s2 < NS; ++s2) o += attnS[h * NS + s2] * vpp[s2 * NDH];
        oS[h * NDH + d] = o;
    }
    __syncthreads();
    // phase 5: attn_out = o @ wo + bo -> preT rows [0,512)
    {
        const int j = tid;
        float ao = bo[j];
        for (int e2 = 0; e2 < NE; ++e2) ao += oS[e2] * wo[e2 * NE + j];
        preT[j * NB + b] = ao;
    }
}

// KB: partial syn GEMM. grid 256 (jt = bid%16, kp = bid/16) x 256
__global__ __launch_bounds__(256) void k_gemm_syn(const float* __restrict__ preT,
                                                  const float* __restrict__ syn_w,
                                                  float* __restrict__ part) {
    const int jt = blockIdx.x & 15, kp = blockIdx.x >> 4;
    const int j = jt * 256 + threadIdx.x;
    float acc[NB];
#pragma unroll
    for (int b = 0; b < NB; ++b) acc[b] = 0.f;
    const int k0 = kp * (NKSYN / NSPLIT), k1 = k0 + (NKSYN / NSPLIT);
    for (int k = k0; k < k1; ++k) {
        const float wv = syn_w[k * NOUT + j];
        const float* pk = preT + k * NB;
#pragma unroll
        for (int b = 0; b < NB; ++b) acc[b] = fmaf(pk[b], wv, acc[b]);
    }
#pragma unroll
    for (int b = 0; b < NB; ++b) part[(kp * NB + b) * NOUT + j] = acc[b];
}

// KC: reduce partials + GLU + LN -> traceBuf[b][pos][:]. grid 64 (b) x 1024
__global__ __launch_bounds__(1024) void k_glu_ln(const float* __restrict__ part,
                                                 const float* __restrict__ syn_b,
                                                 const float* __restrict__ ln_g,
                                                 const float* __restrict__ ln_b,
                                                 float* __restrict__ traceBuf, int pos) {
    __shared__ float red[16];
    const int b = blockIdx.x;
    const int tid = threadIdx.x;
    float g[2];
#pragma unroll
    for (int q = 0; q < 2; ++q) {
        const int n = tid + q * 1024;
        float ya = syn_b[n], yb = syn_b[n + ND];
#pragma unroll
        for (int p = 0; p < NSPLIT; ++p) {
            ya += part[(p * NB + b) * NOUT + n];
            yb += part[(p * NB + b) * NOUT + n + ND];
        }
        g[q] = ya * sigm(yb);
    }
    const float mean = blockReduce<0>(g[0] + g[1], red) * (1.f / ND);
    const float d0 = g[0] - mean, d1 = g[1] - mean;
    const float var = blockReduce<0>(d0 * d0 + d1 * d1, red) * (1.f / ND);
    const float rs = rsqrtf(var + 1e-5f);
#pragma unroll
    for (int q = 0; q < 2; ++q) {
        const int n = tid + q * 1024;
        const float st = (g[q] - mean) * rs * ln_g[n] + ln_b[n];
        traceBuf[(b * NM + pos) * ND + n] = st;
    }
}

// KD: per-neuron NLMs -> act into preT rows [512, 2560). grid 512 x 256
__global__ __launch_bounds__(256) void k_nlm(const float* __restrict__ traceBuf,
                                             const float* __restrict__ w1,
                                             const float* __restrict__ b1,
                                             const float* __restrict__ w2,
                                             const float* __restrict__ b2,
                                             float* __restrict__ preT, int t) {
    const int ni = threadIdx.x & 3;
    const int b = threadIdx.x >> 2;
    const int n = blockIdx.x * 4 + ni;
    float acc[64];
#pragma unroll
    for (int hh = 0; hh < 64; ++hh) acc[hh] = b1[n * 64 + hh];
    int mm = (t + 1) % NM;
#pragma unroll 1
    for (int m = 0; m < NM; ++m) {
        const float tv = traceBuf[(b * NM + mm) * ND + n];
        mm = (mm + 1 == NM) ? 0 : mm + 1;
#pragma unroll
        for (int hh = 0; hh < 64; ++hh) acc[hh] = fmaf(tv, w1[(m * 64 + hh) * ND + n], acc[hh]);
    }
    float z0 = b2[n * 2 + 0], z1 = b2[n * 2 + 1];
#pragma unroll
    for (int i = 0; i < 32; ++i) {
        const float hv = acc[i] * sigm(acc[32 + i]);
        z0 = fmaf(hv, w2[(i * 2 + 0) * ND + n], z0);
        z1 = fmaf(hv, w2[(i * 2 + 1) * ND + n], z1);
    }
    preT[(NE + n) * NB + b] = z0 * sigm(z1);
}

// KS: output sync -> syncT[i][b]. grid 128 x 256
__global__ __launch_bounds__(256) void k_sync_o(const float* __restrict__ preT,
                                                float* __restrict__ aO, float* __restrict__ bO,
                                                const float* __restrict__ r_o,
                                                const int* __restrict__ iol,
                                                const int* __restrict__ ior,
                                                float* __restrict__ syncT) {
    const int idx = blockIdx.x * 256 + threadIdx.x;
    const int b = idx & 63, i = idx >> 6;
    const float av = preT[(NE + iol[i]) * NB + b] * preT[(NE + ior[i]) * NB + b];
    const float r = r_o[i];
    const float aN = r * aO[idx] + av;
    const float bN = r * bO[idx] + 1.f;
    aO[idx] = aN;
    bO[idx] = bN;
    syncT[idx] = aN * rsqrtf(bN);
}

// KE: partial output GEMM. grid 256 x 256
__global__ __launch_bounds__(256) void k_gemm_out(const float* __restrict__ syncT,
                                                  const float* __restrict__ out_w,
                                                  float* __restrict__ part) {
    const int jt = blockIdx.x & 15, kp = blockIdx.x >> 4;
    const int j = jt * 256 + threadIdx.x;
    float acc[NB];
#pragma unroll
    for (int b = 0; b < NB; ++b) acc[b] = 0.f;
    const int k0 = kp * (NE / NSPLIT), k1 = k0 + (NE / NSPLIT);
    for (int k = k0; k < k1; ++k) {
        const float wv = out_w[k * NOUT + j];
        const float* pk = syncT + k * NB;
#pragma unroll
        for (int b = 0; b < NB; ++b) acc[b] = fmaf(pk[b], wv, acc[b]);
    }
#pragma unroll
    for (int b = 0; b < NB; ++b) part[(kp * NB + b) * NOUT + j] = acc[b];
}

// KF: reduce partials + bias -> pred; log_softmax entropy; writes. grid 64 (b) x 1024
__global__ __launch_bounds__(1024) void k_final(const float* __restrict__ part,
                                                const float* __restrict__ out_b,
                                                float* __restrict__ out,
                                                float* __restrict__ predTemp,
                                                int t, int tmode) {
    __shared__ float red[16];
    const int b = blockIdx.x;
    const int tid = threadIdx.x;
    float pr[4];
    float lmax = -1e30f;
#pragma unroll
    for (int q = 0; q < 4; ++q) {
        const int j = tid + q * 1024;
        float v = out_b[j];
#pragma unroll
        for (int p = 0; p < NSPLIT; ++p) v += part[(p * NB + b) * NOUT + j];
        pr[q] = v;
        lmax = fmaxf(lmax, v);
    }
    const float mx = blockReduce<1>(lmax, red);
    float lsum = 0.f;
#pragma unroll
    for (int q = 0; q < 4; ++q) lsum += expf(pr[q] - mx);
    const float se = blockReduce<0>(lsum, red);
    const float logZ = mx + logf(se);
    float lent = 0.f;
#pragma unroll
    for (int q = 0; q < 4; ++q) {
        const float lp = pr[q] - logZ;
        lent += expf(lp) * lp;
    }
    const float ent = blockReduce<0>(lent, red);
    const float ne = -ent * 0.12022458674074694f;  // 1/ln(4096)

    if (tmode) {
#pragma unroll
        for (int q = 0; q < 4; ++q) predTemp[(b * NITER + t) * NOUT + tid + q * 1024] = pr[q];
    } else {
#pragma unroll
        for (int q = 0; q < 4; ++q) {
            const int j = tid + q * 1024;
            out[(b * NOUT + j) * NITER + t] = pr[q];
        }
    }
    if (tid == 0) {
        out[PRED_TOTAL + b * 100 + t] = ne;
        out[PRED_TOTAL + b * 100 + 50 + t] = 1.f - ne;
    }
}

// KT: predTemp (B,T,O) -> out (B,O,T). grid 4096 (b*64 + jchunk) x 256
__global__ __launch_bounds__(256) void k_transpose(const float* __restrict__ predTemp,
                                                   float* __restrict__ out) {
    __shared__ float tile[NS * NITER];  // 64 cols x 50 t = 3200
    const int b = blockIdx.x >> 6;
    const int j0 = (blockIdx.x & 63) * 64;
    for (int i = threadIdx.x; i < 3200; i += 256) {
        const int tt = i >> 6, jj = i & 63;
        tile[jj * NITER + tt] = predTemp[(b * NITER + tt) * NOUT + j0 + jj];
    }
    __syncthreads();
    float* dst = out + (b * NOUT + j0) * NITER;
    for (int i = threadIdx.x; i < 3200; i += 256) dst[i] = tile[i];
}

extern "C" void kernel_launch(void* const* d_in, const int* in_sizes, int n_in,
                              void* d_out, int out_size, void* d_ws, size_t ws_size,
                              hipStream_t stream) {
    const float* x        = (const float*)d_in[0];
    const float* kv_w     = (const float*)d_in[1];
    const float* kv_b     = (const float*)d_in[2];
    const float* kv_ln_g  = (const float*)d_in[3];
    const float* kv_ln_b  = (const float*)d_in[4];
    const float* q_w      = (const float*)d_in[5];
    const float* q_b      = (const float*)d_in[6];
    const float* wq       = (const float*)d_in[7];
    const float* wk       = (const float*)d_in[8];
    const float* wv       = (const float*)d_in[9];
    const float* wo       = (const float*)d_in[10];
    const float* bq       = (const float*)d_in[11];
    const float* bk       = (const float*)d_in[12];
    const float* bv       = (const float*)d_in[13];
    const float* bo       = (const float*)d_in[14];
    const float* syn_w    = (const float*)d_in[15];
    const float* syn_b    = (const float*)d_in[16];
    const float* syn_ln_g = (const float*)d_in[17];
    const float* syn_ln_b = (const float*)d_in[18];
    const float* nlm1_w   = (const float*)d_in[19];
    const float* nlm1_b   = (const float*)d_in[20];
    const float* nlm2_w   = (const float*)d_in[21];
    const float* nlm2_b   = (const float*)d_in[22];
    const float* start_a  = (const float*)d_in[23];
    const float* start_tr = (const float*)d_in[24];
    const float* dec_a    = (const float*)d_in[25];
    const float* dec_o    = (const float*)d_in[26];
    const float* out_w    = (const float*)d_in[27];
    const float* out_b    = (const float*)d_in[28];
    const int* ial        = (const int*)d_in[29];
    const int* iar        = (const int*)d_in[30];
    const int* iol        = (const int*)d_in[31];
    const int* ior        = (const int*)d_in[32];
    float* out = (float*)d_out;

    float* ws = (float*)d_ws;
    size_t off = 0;
    auto alloc = [&](size_t n) { float* p = ws + off; off += n; return p; };
    float* preT     = alloc((size_t)NKSYN * NB);        // 163840
    float* kp_t     = alloc((size_t)NB * NE * NS);      // 2097152
    float* vp_t     = alloc((size_t)NB * NE * NS);
    float* W_qq     = alloc((size_t)NE * NE);
    float* b_qq     = alloc(NE);
    float* r_a      = alloc(NE);
    float* r_o      = alloc(NE);
    float* aA       = alloc((size_t)NB * NE);           // aA,bA,aO,bO contiguous (zero span)
    float* bA       = alloc((size_t)NB * NE);
    float* aO       = alloc((size_t)NB * NE);
    float* bO       = alloc((size_t)NB * NE);
    float* traceBuf = alloc((size_t)NB * NM * ND);      // 3276800
    float* part     = alloc((size_t)NSPLIT * NB * NOUT);// 4194304
    float* syncT    = alloc((size_t)NE * NB);
    int tmode = 0;
    float* predTemp = nullptr;
    if ((off + (size_t)PRED_TOTAL) * sizeof(float) <= ws_size) {
        predTemp = alloc((size_t)PRED_TOTAL);
        tmode = 1;
    }

    k_p0<<<1, 512, 0, stream>>>(dec_a, dec_o, q_b, wq, bq, r_a, r_o, b_qq);
    k_wqq<<<1024, 256, 0, stream>>>(q_w, wq, W_qq);
    k_init_trace<<<(NB * NM * ND) / 256, 256, 0, stream>>>(start_tr, traceBuf);
    k_init_state<<<(2 * NB * ND) / 256, 256, 0, stream>>>(start_a, preT, aA);
    k_p1<<<NB * NS, 512, 0, stream>>>(x, kv_w, kv_b, kv_ln_g, kv_ln_b, wk, bk, wv, bv, kp_t, vp_t);

    for (int t = 0; t < NITER; ++t) {
        k_front<<<NB, 512, 0, stream>>>(preT, aA, bA, r_a, ial, iar, W_qq, b_qq, kp_t, vp_t, wo, bo);
        k_gemm_syn<<<256, 256, 0, stream>>>(preT, syn_w, part);
        k_glu_ln<<<NB, 1024, 0, stream>>>(part, syn_b, syn_ln_g, syn_ln_b, traceBuf, t % NM);
        k_nlm<<<ND / 4, 256, 0, stream>>>(traceBuf, nlm1_w, nlm1_b, nlm2_w, nlm2_b, preT, t);
        k_sync_o<<<(NB * NE) / 256, 256, 0, stream>>>(preT, aO, bO, r_o, iol, ior, syncT);
        k_gemm_out<<<256, 256, 0, stream>>>(syncT, out_w, part);
        k_final<<<NB, 1024, 0, stream>>>(part, out_b, out, predTemp, t, tmode);
    }
    if (tmode) k_transpose<<<NB * 64, 256, 0, stream>>>(predTemp, out);
}